// Round 7
// baseline (2662.283 us; speedup 1.0000x reference)
//
#include <hip/hip_runtime.h>
#include <hip/hip_bf16.h>

// Problem constants
#define TT 2048
#define KK 6
#define EE 32
#define DD 2048
#define FF 1408
#define SS 2
#define CC 384   // TT*KK/EE

typedef __bf16 bf16_t;
typedef __attribute__((ext_vector_type(8))) __bf16 bf16x8;
typedef __attribute__((ext_vector_type(4))) float f32x4;
typedef unsigned int u32;

#define AS1 __attribute__((address_space(1)))
#define AS3 __attribute__((address_space(3)))

__device__ __forceinline__ u32 f2bf(float f) {
    u32 u = __builtin_bit_cast(u32, f);
    return (u + 0x7fffu + ((u >> 16) & 1u)) >> 16;   // RNE, no NaN in data
}
__device__ __forceinline__ u32 pack2(float a, float b) {
    return f2bf(a) | (f2bf(b) << 16);
}
__device__ __forceinline__ float silu_mul(float g, float u) {
    return (g / (1.0f + __expf(-g))) * u;
}

// ---------------- dispatch: pair -> slot (balanced: exactly CC per expert) ----
__global__ void k_dispatch(const int* __restrict__ idx, int* __restrict__ counts,
                           int* __restrict__ tok, int* __restrict__ sop) {
    int p = blockIdx.x * 256 + threadIdx.x;
    if (p >= TT * KK) return;
    int e = idx[p];
    int pos = atomicAdd(&counts[e], 1);
    int slot = e * CC + pos;
    tok[slot] = p / KK;
    sop[p] = slot;
}

// ---------------- gather + fp32->bf16 convert --------------------------------
__global__ void k_gather(const float* __restrict__ x, const int* __restrict__ tok,
                         bf16_t* __restrict__ xall) {
    int row = blockIdx.x;
    int srow = (row < EE * CC) ? tok[row] : (row - EE * CC);
    const float* src = x + (size_t)srow * DD;
    bf16_t* dst = xall + (size_t)row * DD;
    int c0 = threadIdx.x * 8;
    float4 a = *(const float4*)(src + c0);
    float4 b = *(const float4*)(src + c0 + 4);
    uint4 o;
    o.x = pack2(a.x, a.y); o.y = pack2(a.z, a.w);
    o.z = pack2(b.x, b.y); o.w = pack2(b.z, b.w);
    *(uint4*)(dst + c0) = o;
}

#define BSTR 40

// =====================================================================
// Routed grouped GEMM. 512 threads (8 waves, 4m x 2n), M=384 x N=128, BK=32.
// Uniform-loop pipeline, one vmcnt per iter:
//   per iter issue order: stageA(t+1):3 glds, loadB(t+4):8 loads.
//   wait point queue: [B(t+2):8, A(t):3, B(t+3):8] -> vmcnt(8) forces
//   B(t+2)+A(t), leaves B(t+3) in flight. B flight = 2 iters, A = 1 iter.
// 4-slot B register ring. Tail via clamped indices (dummy loads hit L2,
// keep vmcnt counts uniform). LDS 68 KB -> 2 blocks/CU.
// =====================================================================
template<bool FUSED>
__global__ __launch_bounds__(512) void k_gemm_r(
    const bf16_t* __restrict__ Aall, const float* __restrict__ Br,
    bf16_t* __restrict__ Out, int Kdim, int Bstr, int Ostr, int NB)
{
    const int lin = blockIdx.x;
    const int xcd = lin & 7, jj = lin >> 3;
    const int e = xcd + 8 * (jj / NB);     // expert pinned to XCD e%8
    const int nblk = jj % NB;

    const bf16_t* A = Aall + (size_t)e * CC * Kdim;
    const float* Bbase = Br + (size_t)e * Kdim * Bstr;

    const int tid = threadIdx.x;
    const int lane = tid & 63, wid = tid >> 6;
    const int m_base = (wid >> 1) * 96, wn = wid & 1;
    const int l15 = lane & 15, lq = lane >> 4;
    const int arow = tid >> 2, ac = tid & 3;       // A-stage: 128 rows x 4 chunks
    const int bn = tid & 127, kq = tid >> 7;       // B-stage: col, k-quarter

    const float* bsrc;
    bf16_t* Cout;
    if (FUSED) {   // N = 64 gate cols + 64 up cols (same local index)
        bsrc = Bbase + ((bn & 64) ? FF : 0) + nblk * 64 + (bn & 63);
        Cout = Out + (size_t)e * CC * Ostr + nblk * 64;
    } else {
        bsrc = Bbase + nblk * 128 + bn;
        Cout = Out + (size_t)e * CC * Ostr + nblk * 128;
    }

    __shared__ __align__(16) bf16_t As[2][384 * 32];   // 2 x 24 KB
    __shared__ __align__(16) bf16_t Bs[2][128 * BSTR]; // 2 x 10 KB

    f32x4 acc[6][4] = {};
    const int ks = Kdim >> 5;   // 64 (gate_up) or 44 (down)

    auto stageA = [&](int kt, bf16_t* dst) {
        const int k0 = kt << 5;
        #pragma unroll
        for (int i = 0; i < 3; ++i) {
            const int row = i * 128 + arow;
            const int c = ac ^ (arow & 3);                 // src pre-swizzle
            const bf16_t* g = A + (size_t)row * Kdim + (k0 + c * 8);
            AS3 u32* l = (AS3 u32*)(void*)(dst + (size_t)(i * 128 + wid * 16) * 32);
            __builtin_amdgcn_global_load_lds((const AS1 u32*)(const void*)g, l, 16, 0, 0);
        }
    };
    auto loadB = [&](int kt, float* v) {
        const float* sp = bsrc + (size_t)((kt << 5) + kq * 8) * Bstr;
        #pragma unroll
        for (int t = 0; t < 8; ++t) v[t] = sp[(size_t)t * Bstr];
    };
    auto writeB = [&](bf16_t* bbuf, const float* v) {
        uint4 w;
        w.x = pack2(v[0], v[1]); w.y = pack2(v[2], v[3]);
        w.z = pack2(v[4], v[5]); w.w = pack2(v[6], v[7]);
        *(uint4*)(bbuf + (size_t)bn * BSTR + kq * 8) = w;
    };
    auto compute = [&](const bf16_t* abuf, const bf16_t* bbuf) {
        __builtin_amdgcn_s_setprio(1);
        bf16x8 bfr[4];
        #pragma unroll
        for (int j = 0; j < 4; ++j) {
            const int n_ds = FUSED ? (wn * 32 + (j & 1) * 16 + (j >> 1) * 64)
                                   : (wn * 64 + j * 16);
            bfr[j] = *(const bf16x8*)(bbuf + (size_t)(n_ds + l15) * BSTR + lq * 8);
        }
        #pragma unroll
        for (int m = 0; m < 6; ++m) {
            const int row = m_base + m * 16 + l15;
            bf16x8 af = *(const bf16x8*)(abuf + (size_t)row * 32
                           + (size_t)((lq ^ (row & 3)) * 8));
            #pragma unroll
            for (int j = 0; j < 4; ++j)
                acc[m][j] = __builtin_amdgcn_mfma_f32_16x16x32_bf16(af, bfr[j], acc[m][j], 0, 0, 0);
        }
        __builtin_amdgcn_s_setprio(0);
    };

    float r[4][8];

    // ---- prologue: queue must end as [B1, B2, A0, B3] ----
    loadB(0, r[0]);
    asm volatile("s_waitcnt vmcnt(0)" ::: "memory");
    writeB(&Bs[0][0], r[0]);
    loadB(1, r[1]);
    loadB(2, r[2]);
    stageA(0, &As[0][0]);
    loadB(3, r[3]);

    for (int t = 0; t < ks; ++t) {
        asm volatile("s_waitcnt vmcnt(8)" ::: "memory");   // forces B(t+2)+A(t)
        asm volatile("s_waitcnt lgkmcnt(0)" ::: "memory"); // my prior ds_write done
        __builtin_amdgcn_s_barrier();
        const int tn = (t + 1 < ks) ? t + 1 : ks - 1;
        const int tb = (t + 4 < ks) ? t + 4 : ks - 1;
        stageA(tn, &As[(t + 1) & 1][0]);
        loadB(tb, r[(t + 4) & 3]);
        compute(&As[t & 1][0], &Bs[t & 1][0]);
        writeB(&Bs[(t + 1) & 1][0], r[(t + 1) & 3]);
    }

    // ---- epilogue: C/D layout col=lane&15, row=quad*4+reg ----
    if (FUSED) {
        #pragma unroll
        for (int m = 0; m < 6; ++m)
            #pragma unroll
            for (int j = 0; j < 2; ++j) {
                const int n = wn * 32 + j * 16 + l15;
                #pragma unroll
                for (int rr = 0; rr < 4; ++rr) {
                    const int mm = m_base + m * 16 + lq * 4 + rr;
                    Cout[(size_t)mm * Ostr + n] = (bf16_t)silu_mul(acc[m][j][rr], acc[m][j + 2][rr]);
                }
            }
    } else {
        #pragma unroll
        for (int m = 0; m < 6; ++m)
            #pragma unroll
            for (int j = 0; j < 4; ++j) {
                const int n = wn * 64 + j * 16 + l15;
                #pragma unroll
                for (int rr = 0; rr < 4; ++rr) {
                    const int mm = m_base + m * 16 + lq * 4 + rr;
                    Cout[(size_t)mm * Ostr + n] = (bf16_t)acc[m][j][rr];
                }
            }
    }
}

// =====================================================================
// Shared-expert GEMM. 256 threads (4 waves, 2m x 2n), 128x128, BK=32.
// Same uniform pipeline: per iter stageA(t+1):2 glds + loadB(t+4):16 loads;
// vmcnt(16) forces B(t+2)+A(t). LDS 36 KB -> 4 blocks/CU.
// =====================================================================
template<bool FUSED>
__global__ __launch_bounds__(256) void k_gemm_s(
    const bf16_t* __restrict__ Ash, const float* __restrict__ Bsh,
    bf16_t* __restrict__ Out, int Kdim, int Bstr, int Ostr, int ash_stride,
    int nkeys, int KQ, int NBs)
{
    const int b = blockIdx.x;
    const int xcd = b & 7, jj = b >> 3;
    const int m = jj / KQ, kqi = jj % KQ;
    const int key = kqi * 8 + xcd;
    if (key >= nkeys) return;
    const int s = key / NBs, nb = key % NBs;

    const bf16_t* A = Ash + ((size_t)s * ash_stride + (size_t)m * 128) * Kdim;
    const float* Bp = Bsh + (size_t)s * Kdim * Bstr;

    const int tid = threadIdx.x;
    const int lane = tid & 63, wid = tid >> 6;
    const int m_off = (wid >> 1) * 64, wn = wid & 1;
    const int l15 = lane & 15, lq = lane >> 4;
    const int arow = tid >> 2, ac = tid & 3;   // A-stage: 64 rows x 4 chunks / round
    const int bn = tid & 127, kh = tid >> 7;   // B-stage: col, k-half

    const float* bsrc;
    bf16_t* Cout;
    if (FUSED) {
        bsrc = Bp + ((bn & 64) ? FF : 0) + nb * 64 + (bn & 63);
        Cout = Out + ((size_t)s * TT + (size_t)m * 128) * Ostr + nb * 64;
    } else {
        bsrc = Bp + nb * 128 + bn;
        Cout = Out + ((size_t)s * TT + (size_t)m * 128) * Ostr + nb * 128;
    }

    __shared__ __align__(16) bf16_t As[2][128 * 32];   // 2 x 8 KB
    __shared__ __align__(16) bf16_t Bs[2][128 * BSTR]; // 2 x 10 KB

    f32x4 acc[4][4] = {};
    const int ks = Kdim >> 5;

    auto stageA = [&](int kt, bf16_t* dst) {
        const int k0 = kt << 5;
        #pragma unroll
        for (int i = 0; i < 2; ++i) {
            const int row = i * 64 + arow;
            const int c = ac ^ (arow & 3);
            const bf16_t* g = A + (size_t)row * Kdim + (k0 + c * 8);
            AS3 u32* l = (AS3 u32*)(void*)(dst + (size_t)(i * 64 + wid * 16) * 32);
            __builtin_amdgcn_global_load_lds((const AS1 u32*)(const void*)g, l, 16, 0, 0);
        }
    };
    auto loadB = [&](int kt, float* v) {
        const float* sp = bsrc + (size_t)((kt << 5) + kh * 16) * Bstr;
        #pragma unroll
        for (int t = 0; t < 16; ++t) v[t] = sp[(size_t)t * Bstr];
    };
    auto writeB = [&](bf16_t* bbuf, const float* v) {
        u32 p[8];
        #pragma unroll
        for (int t = 0; t < 8; ++t) p[t] = pack2(v[2 * t], v[2 * t + 1]);
        uint4 w0, w1;
        w0.x = p[0]; w0.y = p[1]; w0.z = p[2]; w0.w = p[3];
        w1.x = p[4]; w1.y = p[5]; w1.z = p[6]; w1.w = p[7];
        *(uint4*)(bbuf + (size_t)bn * BSTR + kh * 16) = w0;
        *(uint4*)(bbuf + (size_t)bn * BSTR + kh * 16 + 8) = w1;
    };
    auto compute = [&](const bf16_t* abuf, const bf16_t* bbuf) {
        bf16x8 af[4], bfr[4];
        #pragma unroll
        for (int i = 0; i < 4; ++i) {
            const int row = m_off + i * 16 + l15;
            af[i] = *(const bf16x8*)(abuf + (size_t)row * 32
                       + (size_t)((lq ^ (row & 3)) * 8));
        }
        #pragma unroll
        for (int j = 0; j < 4; ++j) {
            const int n_ds = FUSED ? (wn * 32 + (j & 1) * 16 + (j >> 1) * 64)
                                   : (wn * 64 + j * 16);
            bfr[j] = *(const bf16x8*)(bbuf + (size_t)(n_ds + l15) * BSTR + lq * 8);
        }
        #pragma unroll
        for (int i = 0; i < 4; ++i)
            #pragma unroll
            for (int j = 0; j < 4; ++j)
                acc[i][j] = __builtin_amdgcn_mfma_f32_16x16x32_bf16(af[i], bfr[j], acc[i][j], 0, 0, 0);
    };

    float r[4][16];

    loadB(0, r[0]);
    asm volatile("s_waitcnt vmcnt(0)" ::: "memory");
    writeB(&Bs[0][0], r[0]);
    loadB(1, r[1]);
    loadB(2, r[2]);
    stageA(0, &As[0][0]);
    loadB(3, r[3]);

    for (int t = 0; t < ks; ++t) {
        asm volatile("s_waitcnt vmcnt(16)" ::: "memory");  // forces B(t+2)+A(t)
        asm volatile("s_waitcnt lgkmcnt(0)" ::: "memory");
        __builtin_amdgcn_s_barrier();
        const int tn = (t + 1 < ks) ? t + 1 : ks - 1;
        const int tb = (t + 4 < ks) ? t + 4 : ks - 1;
        stageA(tn, &As[(t + 1) & 1][0]);
        loadB(tb, r[(t + 4) & 3]);
        compute(&As[t & 1][0], &Bs[t & 1][0]);
        writeB(&Bs[(t + 1) & 1][0], r[(t + 1) & 3]);
    }

    if (FUSED) {
        #pragma unroll
        for (int i = 0; i < 4; ++i)
            #pragma unroll
            for (int j = 0; j < 2; ++j) {
                const int n = wn * 32 + j * 16 + l15;
                #pragma unroll
                for (int rr = 0; rr < 4; ++rr) {
                    const int mm = m_off + i * 16 + lq * 4 + rr;
                    Cout[(size_t)mm * Ostr + n] = (bf16_t)silu_mul(acc[i][j][rr], acc[i][j + 2][rr]);
                }
            }
    } else {
        #pragma unroll
        for (int i = 0; i < 4; ++i)
            #pragma unroll
            for (int j = 0; j < 4; ++j) {
                const int n = wn * 64 + j * 16 + l15;
                #pragma unroll
                for (int rr = 0; rr < 4; ++rr) {
                    const int mm = m_off + i * 16 + lq * 4 + rr;
                    Cout[(size_t)mm * Ostr + n] = (bf16_t)acc[i][j][rr];
                }
            }
    }
}

// ---------------- combine: weighted scatter of routed + shared add ----------
__global__ void k_combine(const bf16_t* __restrict__ down, const int* __restrict__ sop,
                          const float* __restrict__ wts, float* __restrict__ y) {
    int t = blockIdx.x;
    int d0 = threadIdx.x * 8;
    float a[8] = {0, 0, 0, 0, 0, 0, 0, 0};
    #pragma unroll
    for (int k = 0; k < KK; ++k) {
        int slot = sop[t * KK + k];
        float w = wts[t * KK + k];
        bf16x8 v = *(const bf16x8*)(down + (size_t)slot * DD + d0);
        #pragma unroll
        for (int j = 0; j < 8; ++j) a[j] += w * (float)v[j];
    }
    #pragma unroll
    for (int s = 0; s < SS; ++s) {
        bf16x8 v = *(const bf16x8*)(down + ((size_t)EE * CC + (size_t)s * TT + t) * DD + d0);
        #pragma unroll
        for (int j = 0; j < 8; ++j) a[j] += (float)v[j];
    }
    float4 o0, o1;
    o0.x = a[0]; o0.y = a[1]; o0.z = a[2]; o0.w = a[3];
    o1.x = a[4]; o1.y = a[5]; o1.z = a[6]; o1.w = a[7];
    *(float4*)(y + (size_t)t * DD + d0) = o0;
    *(float4*)(y + (size_t)t * DD + d0 + 4) = o1;
}

extern "C" void kernel_launch(void* const* d_in, const int* in_sizes, int n_in,
                              void* d_out, int out_size, void* d_ws, size_t ws_size,
                              hipStream_t stream) {
    (void)in_sizes; (void)n_in; (void)out_size; (void)ws_size;
    const float* x      = (const float*)d_in[0];
    const float* wts    = (const float*)d_in[1];
    const float* w_gu   = (const float*)d_in[2];
    const float* w_dn   = (const float*)d_in[3];
    const float* w_gu_s = (const float*)d_in[4];
    const float* w_dn_s = (const float*)d_in[5];
    const int*   indices= (const int*)d_in[6];
    float* y = (float*)d_out;

    char* ws = (char*)d_ws;
    size_t off = 0;
    auto alloc = [&](size_t bytes) {
        void* p = ws + off;
        off = (off + bytes + 255) & ~(size_t)255;
        return p;
    };
    int*    counts = (int*)alloc((size_t)EE * 4);
    int*    tok    = (int*)alloc((size_t)EE * CC * 4);
    int*    sop    = (int*)alloc((size_t)TT * KK * 4);
    bf16_t* xall   = (bf16_t*)alloc((size_t)(EE * CC + TT) * DD * 2);
    bf16_t* actb   = (bf16_t*)alloc((size_t)(EE * CC + SS * TT) * FF * 2);
    bf16_t* dnout  = (bf16_t*)alloc((size_t)(EE * CC + SS * TT) * DD * 2);

    hipMemsetAsync(counts, 0, EE * 4, stream);
    k_dispatch<<<(TT * KK + 255) / 256, 256, 0, stream>>>(indices, counts, tok, sop);
    k_gather<<<EE * CC + TT, 256, 0, stream>>>(x, tok, xall);

    // ---- gate_up (K=DD, B stride 2*FF), silu fused -> actb ----
    k_gemm_r<true><<<EE * 22, 512, 0, stream>>>(xall, w_gu, actb, DD, 2 * FF, FF, 22);
    k_gemm_s<true><<<8 * 6 * 16, 256, 0, stream>>>(
        xall + (size_t)EE * CC * DD, w_gu_s, actb + (size_t)EE * CC * FF,
        DD, 2 * FF, FF, 0, 44, 6, 22);

    // ---- down (K=FF, B stride DD) -> dnout ----
    k_gemm_r<false><<<EE * 16, 512, 0, stream>>>(actb, w_dn, dnout, FF, DD, DD, 16);
    k_gemm_s<false><<<8 * 4 * 16, 256, 0, stream>>>(
        actb + (size_t)EE * CC * FF, w_dn_s, dnout + (size_t)EE * CC * DD,
        FF, DD, DD, TT, 32, 4, 16);

    k_combine<<<TT, 256, 0, stream>>>(dnout, sop, wts, y);
}

// Round 8
// 1548.770 us; speedup vs baseline: 1.7190x; 1.7190x over previous
//
#include <hip/hip_runtime.h>
#include <hip/hip_bf16.h>

// Problem constants
#define TT 2048
#define KK 6
#define EE 32
#define DD 2048
#define FF 1408
#define SS 2
#define CC 384   // TT*KK/EE

typedef __bf16 bf16_t;
typedef __attribute__((ext_vector_type(8))) __bf16 bf16x8;
typedef __attribute__((ext_vector_type(4))) float f32x4;
typedef unsigned int u32;

#define AS1 __attribute__((address_space(1)))
#define AS3 __attribute__((address_space(3)))

__device__ __forceinline__ u32 f2bf(float f) {
    u32 u = __builtin_bit_cast(u32, f);
    return (u + 0x7fffu + ((u >> 16) & 1u)) >> 16;   // RNE, no NaN in data
}
__device__ __forceinline__ u32 pack2(float a, float b) {
    return f2bf(a) | (f2bf(b) << 16);
}
__device__ __forceinline__ float silu_mul(float g, float u) {
    return (g / (1.0f + __expf(-g))) * u;
}

// ---------------- dispatch: pair -> slot (balanced: exactly CC per expert) ----
__global__ void k_dispatch(const int* __restrict__ idx, int* __restrict__ counts,
                           int* __restrict__ tok, int* __restrict__ sop) {
    int p = blockIdx.x * 256 + threadIdx.x;
    if (p >= TT * KK) return;
    int e = idx[p];
    int pos = atomicAdd(&counts[e], 1);
    int slot = e * CC + pos;
    tok[slot] = p / KK;
    sop[p] = slot;
}

// ---------------- gather + fp32->bf16 convert --------------------------------
__global__ void k_gather(const float* __restrict__ x, const int* __restrict__ tok,
                         bf16_t* __restrict__ xall) {
    int row = blockIdx.x;
    int srow = (row < EE * CC) ? tok[row] : (row - EE * CC);
    const float* src = x + (size_t)srow * DD;
    bf16_t* dst = xall + (size_t)row * DD;
    int c0 = threadIdx.x * 8;
    float4 a = *(const float4*)(src + c0);
    float4 b = *(const float4*)(src + c0 + 4);
    uint4 o;
    o.x = pack2(a.x, a.y); o.y = pack2(a.z, a.w);
    o.z = pack2(b.x, b.y); o.w = pack2(b.z, b.w);
    *(uint4*)(dst + c0) = o;
}

#define BSTR 40

// =====================================================================
// Routed grouped GEMM. 512 threads (8 waves, 4m x 2n), M=384 x N=128, BK=32.
// R7 pipeline with STATIC 4-slot register ring (rule #20: no runtime
// indexing -> no scratch). K-loop unrolled x4 (ks=64/44, both %4==0).
// Per sub-iter: loadB(t+4) issued BEFORE the wait; queue at wait =
// [B(t+2):8, A(t):3, B(t+3):8, B(t+4):8] -> vmcnt(16) retires B(t+2)+A(t).
// B flight = 2 iters, A flight = 1 iter, 16 B-reqs in flight during wait.
// =====================================================================
template<bool FUSED>
__global__ __launch_bounds__(512) void k_gemm_r(
    const bf16_t* __restrict__ Aall, const float* __restrict__ Br,
    bf16_t* __restrict__ Out, int Kdim, int Bstr, int Ostr, int NB)
{
    const int lin = blockIdx.x;
    const int xcd = lin & 7, jj = lin >> 3;
    const int e = xcd + 8 * (jj / NB);     // expert pinned to XCD e%8
    const int nblk = jj % NB;

    const bf16_t* A = Aall + (size_t)e * CC * Kdim;
    const float* Bbase = Br + (size_t)e * Kdim * Bstr;

    const int tid = threadIdx.x;
    const int lane = tid & 63, wid = tid >> 6;
    const int m_base = (wid >> 1) * 96, wn = wid & 1;
    const int l15 = lane & 15, lq = lane >> 4;
    const int arow = tid >> 2, ac = tid & 3;       // A-stage: 128 rows x 4 chunks
    const int bn = tid & 127, kq = tid >> 7;       // B-stage: col, k-quarter

    const float* bsrc;
    bf16_t* Cout;
    if (FUSED) {   // N = 64 gate cols + 64 up cols (same local index)
        bsrc = Bbase + ((bn & 64) ? FF : 0) + nblk * 64 + (bn & 63);
        Cout = Out + (size_t)e * CC * Ostr + nblk * 64;
    } else {
        bsrc = Bbase + nblk * 128 + bn;
        Cout = Out + (size_t)e * CC * Ostr + nblk * 128;
    }

    __shared__ __align__(16) bf16_t As[2][384 * 32];   // 2 x 24 KB
    __shared__ __align__(16) bf16_t Bs[2][128 * BSTR]; // 2 x 10 KB

    f32x4 acc[6][4] = {};
    const int ks = Kdim >> 5;   // 64 (gate_up) or 44 (down)

    auto stageA = [&](int kt, bf16_t* dst) {
        const int k0 = kt << 5;
        #pragma unroll
        for (int i = 0; i < 3; ++i) {
            const int row = i * 128 + arow;
            const int c = ac ^ (arow & 3);                 // src pre-swizzle
            const bf16_t* g = A + (size_t)row * Kdim + (k0 + c * 8);
            AS3 u32* l = (AS3 u32*)(void*)(dst + (size_t)(i * 128 + wid * 16) * 32);
            __builtin_amdgcn_global_load_lds((const AS1 u32*)(const void*)g, l, 16, 0, 0);
        }
    };
    auto loadB = [&](int kt, float* v) {
        const float* sp = bsrc + (size_t)((kt << 5) + kq * 8) * Bstr;
        #pragma unroll
        for (int t = 0; t < 8; ++t) v[t] = sp[(size_t)t * Bstr];
    };
    auto writeB = [&](bf16_t* bbuf, const float* v) {
        uint4 w;
        w.x = pack2(v[0], v[1]); w.y = pack2(v[2], v[3]);
        w.z = pack2(v[4], v[5]); w.w = pack2(v[6], v[7]);
        *(uint4*)(bbuf + (size_t)bn * BSTR + kq * 8) = w;
    };
    auto compute = [&](const bf16_t* abuf, const bf16_t* bbuf) {
        __builtin_amdgcn_s_setprio(1);
        bf16x8 bfr[4];
        #pragma unroll
        for (int j = 0; j < 4; ++j) {
            const int n_ds = FUSED ? (wn * 32 + (j & 1) * 16 + (j >> 1) * 64)
                                   : (wn * 64 + j * 16);
            bfr[j] = *(const bf16x8*)(bbuf + (size_t)(n_ds + l15) * BSTR + lq * 8);
        }
        #pragma unroll
        for (int m = 0; m < 6; ++m) {
            const int row = m_base + m * 16 + l15;
            bf16x8 af = *(const bf16x8*)(abuf + (size_t)row * 32
                           + (size_t)((lq ^ (row & 3)) * 8));
            #pragma unroll
            for (int j = 0; j < 4; ++j)
                acc[m][j] = __builtin_amdgcn_mfma_f32_16x16x32_bf16(af, bfr[j], acc[m][j], 0, 0, 0);
        }
        __builtin_amdgcn_s_setprio(0);
    };

    float r0[8], r1[8], r2[8], r3[8];
    bf16_t* const As0 = &As[0][0];  bf16_t* const As1 = &As[1][0];
    bf16_t* const Bs0 = &Bs[0][0];  bf16_t* const Bs1 = &Bs[1][0];

    // ---- prologue: queue ends as [B1:8, B2:8, A0:3, B3:8] = 27 ----
    loadB(0, r0);
    asm volatile("s_waitcnt vmcnt(0)" ::: "memory");
    writeB(Bs0, r0);
    loadB(1, r1);
    loadB(2, r2);
    stageA(0, As0);
    loadB(3, r3);

#define R_ITER(T, RLOAD, RWRITE, ASC, ASN, BSC, BSN)                      \
    {                                                                     \
        const int tb = ((T) + 4 < ks) ? (T) + 4 : ks - 1;                 \
        loadB(tb, RLOAD);                                                 \
        asm volatile("s_waitcnt vmcnt(16)" ::: "memory");                 \
        asm volatile("s_waitcnt lgkmcnt(0)" ::: "memory");                \
        __builtin_amdgcn_s_barrier();                                     \
        const int tn = ((T) + 1 < ks) ? (T) + 1 : ks - 1;                 \
        stageA(tn, ASN);                                                  \
        compute(ASC, BSC);                                                \
        writeB(BSN, RWRITE);                                              \
    }

    for (int t = 0; t < ks; t += 4) {
        R_ITER(t + 0, r0, r1, As0, As1, Bs0, Bs1);
        R_ITER(t + 1, r1, r2, As1, As0, Bs1, Bs0);
        R_ITER(t + 2, r2, r3, As0, As1, Bs0, Bs1);
        R_ITER(t + 3, r3, r0, As1, As0, Bs1, Bs0);
    }
#undef R_ITER

    // ---- epilogue: C/D layout col=lane&15, row=quad*4+reg ----
    if (FUSED) {
        #pragma unroll
        for (int m = 0; m < 6; ++m)
            #pragma unroll
            for (int j = 0; j < 2; ++j) {
                const int n = wn * 32 + j * 16 + l15;
                #pragma unroll
                for (int rr = 0; rr < 4; ++rr) {
                    const int mm = m_base + m * 16 + lq * 4 + rr;
                    Cout[(size_t)mm * Ostr + n] = (bf16_t)silu_mul(acc[m][j][rr], acc[m][j + 2][rr]);
                }
            }
    } else {
        #pragma unroll
        for (int m = 0; m < 6; ++m)
            #pragma unroll
            for (int j = 0; j < 4; ++j) {
                const int n = wn * 64 + j * 16 + l15;
                #pragma unroll
                for (int rr = 0; rr < 4; ++rr) {
                    const int mm = m_base + m * 16 + lq * 4 + rr;
                    Cout[(size_t)mm * Ostr + n] = (bf16_t)acc[m][j][rr];
                }
            }
    }
}

// =====================================================================
// Shared-expert GEMM. 256 threads (4 waves, 2m x 2n), 128x128, BK=32.
// Same static-ring pipeline: per iter loadB(t+4):16 early, vmcnt(32)
// retires B(t+2):16 + A(t):2. LDS 36 KB.
// =====================================================================
template<bool FUSED>
__global__ __launch_bounds__(256) void k_gemm_s(
    const bf16_t* __restrict__ Ash, const float* __restrict__ Bsh,
    bf16_t* __restrict__ Out, int Kdim, int Bstr, int Ostr, int ash_stride,
    int nkeys, int KQ, int NBs)
{
    const int b = blockIdx.x;
    const int xcd = b & 7, jj = b >> 3;
    const int m = jj / KQ, kqi = jj % KQ;
    const int key = kqi * 8 + xcd;
    if (key >= nkeys) return;
    const int s = key / NBs, nb = key % NBs;

    const bf16_t* A = Ash + ((size_t)s * ash_stride + (size_t)m * 128) * Kdim;
    const float* Bp = Bsh + (size_t)s * Kdim * Bstr;

    const int tid = threadIdx.x;
    const int lane = tid & 63, wid = tid >> 6;
    const int m_off = (wid >> 1) * 64, wn = wid & 1;
    const int l15 = lane & 15, lq = lane >> 4;
    const int arow = tid >> 2, ac = tid & 3;   // A-stage: 64 rows x 4 chunks
    const int bn = tid & 127, kh = tid >> 7;   // B-stage: col, k-half

    const float* bsrc;
    bf16_t* Cout;
    if (FUSED) {
        bsrc = Bp + ((bn & 64) ? FF : 0) + nb * 64 + (bn & 63);
        Cout = Out + ((size_t)s * TT + (size_t)m * 128) * Ostr + nb * 64;
    } else {
        bsrc = Bp + nb * 128 + bn;
        Cout = Out + ((size_t)s * TT + (size_t)m * 128) * Ostr + nb * 128;
    }

    __shared__ __align__(16) bf16_t As[2][128 * 32];   // 2 x 8 KB
    __shared__ __align__(16) bf16_t Bs[2][128 * BSTR]; // 2 x 10 KB

    f32x4 acc[4][4] = {};
    const int ks = Kdim >> 5;   // 64 or 44, both %4==0

    auto stageA = [&](int kt, bf16_t* dst) {
        const int k0 = kt << 5;
        #pragma unroll
        for (int i = 0; i < 2; ++i) {
            const int row = i * 64 + arow;
            const int c = ac ^ (arow & 3);
            const bf16_t* g = A + (size_t)row * Kdim + (k0 + c * 8);
            AS3 u32* l = (AS3 u32*)(void*)(dst + (size_t)(i * 64 + wid * 16) * 32);
            __builtin_amdgcn_global_load_lds((const AS1 u32*)(const void*)g, l, 16, 0, 0);
        }
    };
    auto loadB = [&](int kt, float* v) {
        const float* sp = bsrc + (size_t)((kt << 5) + kh * 16) * Bstr;
        #pragma unroll
        for (int t = 0; t < 16; ++t) v[t] = sp[(size_t)t * Bstr];
    };
    auto writeB = [&](bf16_t* bbuf, const float* v) {
        u32 p[8];
        #pragma unroll
        for (int t = 0; t < 8; ++t) p[t] = pack2(v[2 * t], v[2 * t + 1]);
        uint4 w0, w1;
        w0.x = p[0]; w0.y = p[1]; w0.z = p[2]; w0.w = p[3];
        w1.x = p[4]; w1.y = p[5]; w1.z = p[6]; w1.w = p[7];
        *(uint4*)(bbuf + (size_t)bn * BSTR + kh * 16) = w0;
        *(uint4*)(bbuf + (size_t)bn * BSTR + kh * 16 + 8) = w1;
    };
    auto compute = [&](const bf16_t* abuf, const bf16_t* bbuf) {
        bf16x8 af[4], bfr[4];
        #pragma unroll
        for (int i = 0; i < 4; ++i) {
            const int row = m_off + i * 16 + l15;
            af[i] = *(const bf16x8*)(abuf + (size_t)row * 32
                       + (size_t)((lq ^ (row & 3)) * 8));
        }
        #pragma unroll
        for (int j = 0; j < 4; ++j) {
            const int n_ds = FUSED ? (wn * 32 + (j & 1) * 16 + (j >> 1) * 64)
                                   : (wn * 64 + j * 16);
            bfr[j] = *(const bf16x8*)(bbuf + (size_t)(n_ds + l15) * BSTR + lq * 8);
        }
        #pragma unroll
        for (int i = 0; i < 4; ++i)
            #pragma unroll
            for (int j = 0; j < 4; ++j)
                acc[i][j] = __builtin_amdgcn_mfma_f32_16x16x32_bf16(af[i], bfr[j], acc[i][j], 0, 0, 0);
    };

    float r0[16], r1[16], r2[16], r3[16];
    bf16_t* const As0 = &As[0][0];  bf16_t* const As1 = &As[1][0];
    bf16_t* const Bs0 = &Bs[0][0];  bf16_t* const Bs1 = &Bs[1][0];

    // ---- prologue: queue ends as [B1:16, B2:16, A0:2, B3:16] = 50 ----
    loadB(0, r0);
    asm volatile("s_waitcnt vmcnt(0)" ::: "memory");
    writeB(Bs0, r0);
    loadB(1, r1);
    loadB(2, r2);
    stageA(0, As0);
    loadB(3, r3);

#define S_ITER(T, RLOAD, RWRITE, ASC, ASN, BSC, BSN)                      \
    {                                                                     \
        const int tb = ((T) + 4 < ks) ? (T) + 4 : ks - 1;                 \
        loadB(tb, RLOAD);                                                 \
        asm volatile("s_waitcnt vmcnt(32)" ::: "memory");                 \
        asm volatile("s_waitcnt lgkmcnt(0)" ::: "memory");                \
        __builtin_amdgcn_s_barrier();                                     \
        const int tn = ((T) + 1 < ks) ? (T) + 1 : ks - 1;                 \
        stageA(tn, ASN);                                                  \
        compute(ASC, BSC);                                                \
        writeB(BSN, RWRITE);                                              \
    }

    for (int t = 0; t < ks; t += 4) {
        S_ITER(t + 0, r0, r1, As0, As1, Bs0, Bs1);
        S_ITER(t + 1, r1, r2, As1, As0, Bs1, Bs0);
        S_ITER(t + 2, r2, r3, As0, As1, Bs0, Bs1);
        S_ITER(t + 3, r3, r0, As1, As0, Bs1, Bs0);
    }
#undef S_ITER

    if (FUSED) {
        #pragma unroll
        for (int i = 0; i < 4; ++i)
            #pragma unroll
            for (int j = 0; j < 2; ++j) {
                const int n = wn * 32 + j * 16 + l15;
                #pragma unroll
                for (int rr = 0; rr < 4; ++rr) {
                    const int mm = m_off + i * 16 + lq * 4 + rr;
                    Cout[(size_t)mm * Ostr + n] = (bf16_t)silu_mul(acc[i][j][rr], acc[i][j + 2][rr]);
                }
            }
    } else {
        #pragma unroll
        for (int i = 0; i < 4; ++i)
            #pragma unroll
            for (int j = 0; j < 4; ++j) {
                const int n = wn * 64 + j * 16 + l15;
                #pragma unroll
                for (int rr = 0; rr < 4; ++rr) {
                    const int mm = m_off + i * 16 + lq * 4 + rr;
                    Cout[(size_t)mm * Ostr + n] = (bf16_t)acc[i][j][rr];
                }
            }
    }
}

// ---------------- combine: weighted scatter of routed + shared add ----------
__global__ void k_combine(const bf16_t* __restrict__ down, const int* __restrict__ sop,
                          const float* __restrict__ wts, float* __restrict__ y) {
    int t = blockIdx.x;
    int d0 = threadIdx.x * 8;
    float a[8] = {0, 0, 0, 0, 0, 0, 0, 0};
    #pragma unroll
    for (int k = 0; k < KK; ++k) {
        int slot = sop[t * KK + k];
        float w = wts[t * KK + k];
        bf16x8 v = *(const bf16x8*)(down + (size_t)slot * DD + d0);
        #pragma unroll
        for (int j = 0; j < 8; ++j) a[j] += w * (float)v[j];
    }
    #pragma unroll
    for (int s = 0; s < SS; ++s) {
        bf16x8 v = *(const bf16x8*)(down + ((size_t)EE * CC + (size_t)s * TT + t) * DD + d0);
        #pragma unroll
        for (int j = 0; j < 8; ++j) a[j] += (float)v[j];
    }
    float4 o0, o1;
    o0.x = a[0]; o0.y = a[1]; o0.z = a[2]; o0.w = a[3];
    o1.x = a[4]; o1.y = a[5]; o1.z = a[6]; o1.w = a[7];
    *(float4*)(y + (size_t)t * DD + d0) = o0;
    *(float4*)(y + (size_t)t * DD + d0 + 4) = o1;
}

extern "C" void kernel_launch(void* const* d_in, const int* in_sizes, int n_in,
                              void* d_out, int out_size, void* d_ws, size_t ws_size,
                              hipStream_t stream) {
    (void)in_sizes; (void)n_in; (void)out_size; (void)ws_size;
    const float* x      = (const float*)d_in[0];
    const float* wts    = (const float*)d_in[1];
    const float* w_gu   = (const float*)d_in[2];
    const float* w_dn   = (const float*)d_in[3];
    const float* w_gu_s = (const float*)d_in[4];
    const float* w_dn_s = (const float*)d_in[5];
    const int*   indices= (const int*)d_in[6];
    float* y = (float*)d_out;

    char* ws = (char*)d_ws;
    size_t off = 0;
    auto alloc = [&](size_t bytes) {
        void* p = ws + off;
        off = (off + bytes + 255) & ~(size_t)255;
        return p;
    };
    int*    counts = (int*)alloc((size_t)EE * 4);
    int*    tok    = (int*)alloc((size_t)EE * CC * 4);
    int*    sop    = (int*)alloc((size_t)TT * KK * 4);
    bf16_t* xall   = (bf16_t*)alloc((size_t)(EE * CC + TT) * DD * 2);
    bf16_t* actb   = (bf16_t*)alloc((size_t)(EE * CC + SS * TT) * FF * 2);
    bf16_t* dnout  = (bf16_t*)alloc((size_t)(EE * CC + SS * TT) * DD * 2);

    hipMemsetAsync(counts, 0, EE * 4, stream);
    k_dispatch<<<(TT * KK + 255) / 256, 256, 0, stream>>>(indices, counts, tok, sop);
    k_gather<<<EE * CC + TT, 256, 0, stream>>>(x, tok, xall);

    // ---- gate_up (K=DD, B stride 2*FF), silu fused -> actb ----
    k_gemm_r<true><<<EE * 22, 512, 0, stream>>>(xall, w_gu, actb, DD, 2 * FF, FF, 22);
    k_gemm_s<true><<<8 * 6 * 16, 256, 0, stream>>>(
        xall + (size_t)EE * CC * DD, w_gu_s, actb + (size_t)EE * CC * FF,
        DD, 2 * FF, FF, 0, 44, 6, 22);

    // ---- down (K=FF, B stride DD) -> dnout ----
    k_gemm_r<false><<<EE * 16, 512, 0, stream>>>(actb, w_dn, dnout, FF, DD, DD, 16);
    k_gemm_s<false><<<8 * 4 * 16, 256, 0, stream>>>(
        actb + (size_t)EE * CC * FF, w_dn_s, dnout + (size_t)EE * CC * DD,
        FF, DD, DD, TT, 32, 4, 16);

    k_combine<<<TT, 256, 0, stream>>>(dnout, sop, wts, y);
}